// Round 17
// baseline (1193.349 us; speedup 1.0000x reference)
//
#include <hip/hip_runtime.h>
#include <float.h>

#define KC 4096
#define DIM 256
#define MB 16384            // m per batch element (16*32*32)
#define NTOT 65536          // rows
#define ZELEMS 16777216
#define LOSS_OFF 16777216
#define IDX_OFF  16777217
// TAU: 2*(grid ULP(256)=3.05e-5) + 2*fp16-chain score err (<=4.7e-5 worst) + slack.
// Validated empirically at 1.5e-4 in R11-R16 (0 misses across 65536 rows).
#define TAU 1.5e-4f

// scratch inside z_q output region (fully overwritten by vq_apply at the end):
// [0, 524288)       fp16 e' A-fragment table (2MB)
#define BT_OFF   524288     // f32 |e_k|^2 table, 4096 floats
#define CNT_OFF  528400     // 2 uints (cand count, full count)
#define CAND_OFF 532480     // uint4 entries (16B each), cap 65536
#define FULL_OFF 800000     // uint entries, cap 65536

typedef _Float16 h8 __attribute__((ext_vector_type(8)));
typedef float f4v __attribute__((ext_vector_type(4)));

__device__ __forceinline__ bool lexlt(float av, int ai, float bv, int bi) {
    return (av < bv) || (av == bv && ai < bi);
}

// ---- P: fused prep. Blocks 0-511: fp16 e'=e*4096 A-frag table (R10-R16
// verified geometry). Blocks 512-1535: |e|^2 (fp64->f32), one wave per code. ----
__global__ __launch_bounds__(256) void vq_prep(const float* __restrict__ e,
                                               float* __restrict__ out) {
    if (blockIdx.x < 512) {
        int t = blockIdx.x * 256 + threadIdx.x;        // 0..131071
        int code = t >> 5, s8 = t & 31;
        const float4* src = reinterpret_cast<const float4*>(e + (size_t)code * DIM + s8 * 8);
        float4 v0 = src[0], v1 = src[1];
        float f[8] = {v0.x, v0.y, v0.z, v0.w, v1.x, v1.y, v1.z, v1.w};
        union { uint4 q; _Float16 h[8]; } P;
        #pragma unroll
        for (int p = 0; p < 8; ++p) P.h[p] = (_Float16)(f[p] * 4096.0f);
        int kc = s8 >> 2, khi = s8 & 3;
        int lane = khi * 16 + (code & 15);
        int slot = ((code >> 4) * 8 + kc) * 64 + lane;
        reinterpret_cast<uint4*>(out)[slot] = P.q;
    } else {
        int k = (blockIdx.x - 512) * 4 + (threadIdx.x >> 6);   // 0..4095
        int lane = threadIdx.x & 63;
        float4 v = reinterpret_cast<const float4*>(e + (size_t)k * DIM)[lane];
        double s = (double)v.x * v.x + (double)v.y * v.y + (double)v.z * v.z + (double)v.w * v.w;
        #pragma unroll
        for (int off = 32; off > 0; off >>= 1) s += __shfl_down(s, off);
        if (lane == 0) out[BT_OFF + k] = (float)s;
    }
}

// push (value,k) into the 4-slot per-lane list (if-chain: no runtime indexing)
#define PUSH(C, V0, V1, V2, V3, L0, L1, L2, L3, v, k)                           \
    { if (C == 0) { V0 = v; L0 = k; } else if (C == 1) { V1 = v; L1 = k; }      \
      else if (C == 2) { V2 = v; L2 = k; } else if (C == 3) { V3 = v; L3 = k; } \
      C++; }

// ---- K1: fp16 MFMA, SINGLE-PASS exact-window. Block = 128 rows (4w x 32r).
// Per lane: (b1,bk) + <=4 (value,k) candidates: every non-record score within
// tau of the RUNNING min, plus displaced records within tau of displacer.
// Superset of the true window (running min >= final min); exact-filtered at
// the end against FINAL gb1+TAU. Overflow (>4 pushes) -> full scan. ----
__global__ __launch_bounds__(256) void vq_fast(const float* __restrict__ z,
                                               float* __restrict__ out) {
    __shared__ uint4 etile[2][512];                // 16KB double-buffered tile
    __shared__ unsigned long long lists[4][32][4]; // (wave,row,khi) packed lists
    const int tid = threadIdx.x;
    const int wave = tid >> 6, lane = tid & 63;
    const int khi = lane >> 4, l16 = lane & 15;
    const int nbase = blockIdx.x * 128;
    const int b = nbase / MB;
    const int mbase = nbase % MB;
    const float* zb = z + (size_t)b * DIM * MB + mbase + wave * 32 + l16;

    // z B-fragments (fp16), 2 row-sets x 8 kc
    h8 zf0[8], zf1[8];
    #pragma unroll
    for (int kc = 0; kc < 8; ++kc) {
        h8 va, vb;
        #pragma unroll
        for (int j = 0; j < 8; ++j) {
            size_t off = (size_t)(kc * 32 + khi * 8 + j) * MB;
            va[j] = (_Float16)zb[off];
            vb[j] = (_Float16)zb[off + 16];
        }
        zf0[kc] = va; zf1[kc] = vb;
    }

    const uint4* ET = reinterpret_cast<const uint4*>(out);
    const float* Btab = out + BT_OFF;

    float b10 = FLT_MAX, b11 = FLT_MAX;
    int bk0 = 0, bk1 = 0;
    int c0 = 0, c1 = 0;
    float v00 = 0.f, v01 = 0.f, v02 = 0.f, v03 = 0.f;
    float v10 = 0.f, v11 = 0.f, v12 = 0.f, v13 = 0.f;
    int l00 = 0, l01 = 0, l02 = 0, l03 = 0;
    int l10 = 0, l11 = 0, l12 = 0, l13 = 0;

    uint4 r0 = ET[tid], r1 = ET[tid + 256];        // preload tile 0
    for (int tile = 0; tile < KC / 16; ++tile) {
        const int cur = tile & 1;
        etile[cur][tid] = r0; etile[cur][tid + 256] = r1;
        __syncthreads();                           // ONLY barrier per tile:
        // write(t+2) to this buffer is separated from read(t) by barrier(t+1)
        if (tile < KC / 16 - 1) {
            r0 = ET[(size_t)(tile + 1) * 512 + tid];
            r1 = ET[(size_t)(tile + 1) * 512 + tid + 256];
        }

        f4v a0 = {0.f, 0.f, 0.f, 0.f}, a1 = a0;
        #pragma unroll
        for (int kc = 0; kc < 8; ++kc) {
            union { uint4 q; h8 v; } af;
            af.q = etile[cur][kc * 64 + lane];
            a0 = __builtin_amdgcn_mfma_f32_16x16x32_f16(af.v, zf0[kc], a0, 0, 0, 0);
            a1 = __builtin_amdgcn_mfma_f32_16x16x32_f16(af.v, zf1[kc], a1, 0, 0, 0);
        }

        const f4v Bv = *reinterpret_cast<const f4v*>(Btab + tile * 16 + khi * 4);
        const int kb = tile * 16 + khi * 4;
        float sc0[4], sc1[4];
        #pragma unroll
        for (int i = 0; i < 4; ++i) {
            sc0[i] = fmaf(-4.8828125e-4f, a0[i], Bv[i]);   // -1/2048 exact
            sc1[i] = fmaf(-4.8828125e-4f, a1[i], Bv[i]);
        }
        float m0 = fminf(fminf(sc0[0], sc0[1]), fminf(sc0[2], sc0[3]));
        if (m0 <= b10 + TAU) {                     // rare: detail insert
            #pragma unroll
            for (int i = 0; i < 4; ++i) {
                float s = sc0[i]; int k = kb + i;  // ascending k per lane
                if (s < b10) {
                    if (b10 <= s + TAU) PUSH(c0, v00, v01, v02, v03, l00, l01, l02, l03, b10, bk0)
                    b10 = s; bk0 = k;
                } else if (s <= b10 + TAU) {
                    PUSH(c0, v00, v01, v02, v03, l00, l01, l02, l03, s, k)
                }
            }
        }
        float m1 = fminf(fminf(sc1[0], sc1[1]), fminf(sc1[2], sc1[3]));
        if (m1 <= b11 + TAU) {
            #pragma unroll
            for (int i = 0; i < 4; ++i) {
                float s = sc1[i]; int k = kb + i;
                if (s < b11) {
                    if (b11 <= s + TAU) PUSH(c1, v10, v11, v12, v13, l10, l11, l12, l13, b11, bk1)
                    b11 = s; bk1 = k;
                } else if (s <= b11 + TAU) {
                    PUSH(c1, v10, v11, v12, v13, l10, l11, l12, l13, s, k)
                }
            }
        }
    }

    // merge top-1 across the 4 khi groups (lex), keep own (b1,bk) intact
    float gb0 = b10, gb1 = b11;
    int gk0 = bk0, gk1 = bk1;
    #pragma unroll
    for (int off = 16; off < 64; off <<= 1) {
        float ov = __shfl_xor(gb0, off); int ok = __shfl_xor(gk0, off);
        if (lexlt(ov, ok, gb0, gk0)) { gb0 = ov; gk0 = ok; }
        ov = __shfl_xor(gb1, off); ok = __shfl_xor(gk1, off);
        if (lexlt(ov, ok, gb1, gk1)) { gb1 = ov; gk1 = ok; }
    }
    const float thr0 = gb0 + TAU, thr1 = gb1 + TAU;

    // exact-filter own entries vs FINAL threshold, pack (<=4 ks + count)
    int n0 = 0, pa0 = 0, pb0 = 0, pc0 = 0, pd0 = 0;
    #define ADD0(kk) { if (n0 == 0) pa0 = kk; else if (n0 == 1) pb0 = kk; \
                       else if (n0 == 2) pc0 = kk; else if (n0 == 3) pd0 = kk; n0++; }
    if (b10 <= thr0) ADD0(bk0)
    if (c0 > 0 && v00 <= thr0) ADD0(l00)
    if (c0 > 1 && v01 <= thr0) ADD0(l01)
    if (c0 > 2 && v02 <= thr0) ADD0(l02)
    if (c0 > 3 && v03 <= thr0) ADD0(l03)
    int tot0 = (c0 > 4) ? 15 : n0;                 // overflow -> force full
    int n1 = 0, pa1 = 0, pb1 = 0, pc1 = 0, pd1 = 0;
    #define ADD1(kk) { if (n1 == 0) pa1 = kk; else if (n1 == 1) pb1 = kk; \
                       else if (n1 == 2) pc1 = kk; else if (n1 == 3) pd1 = kk; n1++; }
    if (b11 <= thr1) ADD1(bk1)
    if (c1 > 0 && v10 <= thr1) ADD1(l10)
    if (c1 > 1 && v11 <= thr1) ADD1(l11)
    if (c1 > 2 && v12 <= thr1) ADD1(l12)
    if (c1 > 3 && v13 <= thr1) ADD1(l13)
    int tot1 = (c1 > 4) ? 15 : n1;
    lists[wave][l16][khi] = ((unsigned long long)tot0 << 48) |
        (unsigned long long)pa0 | ((unsigned long long)pb0 << 12) |
        ((unsigned long long)pc0 << 24) | ((unsigned long long)pd0 << 36);
    lists[wave][16 + l16][khi] = ((unsigned long long)tot1 << 48) |
        (unsigned long long)pa1 | ((unsigned long long)pb1 << 12) |
        ((unsigned long long)pc1 << 24) | ((unsigned long long)pd1 << 36);
    __syncthreads();

    // gather + classify + emit (lanes<16 own one row per set)
    unsigned* cntg = (unsigned*)(out + CNT_OFF);
    #pragma unroll
    for (int set = 0; set < 2; ++set) {
        bool act = (lane < 16);
        int gidx = nbase + wave * 32 + set * 16 + l16;
        int I1 = set ? gk1 : gk0;
        int tot = 0, c[4];
        c[0] = c[1] = c[2] = c[3] = I1;            // pad with best (harmless dup)
        if (act) {
            #pragma unroll
            for (int q = 0; q < 4; ++q) {
                unsigned long long pl = lists[wave][set * 16 + l16][q];
                int pc = (int)(pl >> 48);
                #pragma unroll
                for (int j = 0; j < 4; ++j) {
                    int kv = (int)((pl >> (12 * j)) & 4095ull);
                    if (j < pc && tot + j < 4) c[tot + j] = kv;
                }
                tot += pc;
            }
            out[IDX_OFF + gidx] = (float)I1;       // final for clean; placeholder else
        }
        bool cand = act && (tot >= 2) && (tot <= 4);
        bool full = act && (tot > 4);
        unsigned long long mc = __ballot(cand);
        if (mc) {
            int leader = __ffsll((long long)mc) - 1;
            unsigned base = 0;
            if (lane == leader) base = atomicAdd(cntg, (unsigned)__popcll(mc));
            base = __shfl(base, leader);
            if (cand) {
                unsigned pos = base + (unsigned)__popcll(mc & ((1ull << lane) - 1ull));
                reinterpret_cast<uint4*>(out + CAND_OFF)[pos] =
                    make_uint4((unsigned)gidx,
                               (unsigned)c[0] | ((unsigned)c[1] << 16),
                               (unsigned)c[2] | ((unsigned)c[3] << 16), 0u);
            }
        }
        unsigned long long mf = __ballot(full);
        if (mf) {
            int leader = __ffsll((long long)mf) - 1;
            unsigned base = 0;
            if (lane == leader) base = atomicAdd(cntg + 1, (unsigned)__popcll(mf));
            base = __shfl(base, leader);
            if (full) {
                unsigned pos = base + (unsigned)__popcll(mf & ((1ull << lane) - 1ull));
                reinterpret_cast<unsigned*>(out + FULL_OFF)[pos] = (unsigned)gidx;
            }
        }
    }
}

// ---- K2a: candidate rescore (<=4 codes), grid-stride waves (R12-proven) ----
__global__ __launch_bounds__(256) void vq_resolve_cand(const float* __restrict__ z,
                                                       const float* __restrict__ e,
                                                       float* __restrict__ out) {
    const int wave = threadIdx.x >> 6, lane = threadIdx.x & 63;
    const unsigned n = *reinterpret_cast<const unsigned*>(out + CNT_OFF);
    const uint4* list = reinterpret_cast<const uint4*>(out + CAND_OFF);
    for (unsigned ei = blockIdx.x * 4 + wave; ei < n; ei += gridDim.x * 4) {
        uint4 ent = list[ei];
        const int gidx = (int)ent.x;
        const int c1 = (int)(ent.y & 0xFFFFu), c2 = (int)(ent.y >> 16);
        const int c3 = (int)(ent.z & 0xFFFFu), c4 = (int)(ent.z >> 16);
        const int b = gidx >> 14, m = gidx & (MB - 1);
        const float* zr = z + (size_t)b * DIM * MB + m;
        const float* e1 = e + (size_t)c1 * DIM;
        const float* e2 = e + (size_t)c2 * DIM;
        const float* e3 = e + (size_t)c3 * DIM;
        const float* e4 = e + (size_t)c4 * DIM;
        double A = 0.0;
        double d1 = 0.0, d2 = 0.0, d3 = 0.0, d4 = 0.0;
        double q1 = 0.0, q2 = 0.0, q3 = 0.0, q4 = 0.0;
        #pragma unroll
        for (int jj = 0; jj < 4; ++jj) {
            int d = lane * 4 + jj;
            double zv = (double)zr[(size_t)d * MB];
            double v1 = (double)e1[d], v2 = (double)e2[d];
            double v3 = (double)e3[d], v4 = (double)e4[d];
            A = fma(zv, zv, A);
            d1 = fma(zv, v1, d1); q1 = fma(v1, v1, q1);
            d2 = fma(zv, v2, d2); q2 = fma(v2, v2, q2);
            d3 = fma(zv, v3, d3); q3 = fma(v3, v3, q3);
            d4 = fma(zv, v4, d4); q4 = fma(v4, v4, q4);
        }
        #pragma unroll
        for (int mm = 1; mm < 64; mm <<= 1) {
            A += __shfl_xor(A, mm);
            d1 += __shfl_xor(d1, mm); q1 += __shfl_xor(q1, mm);
            d2 += __shfl_xor(d2, mm); q2 += __shfl_xor(q2, mm);
            d3 += __shfl_xor(d3, mm); q3 += __shfl_xor(q3, mm);
            d4 += __shfl_xor(d4, mm); q4 += __shfl_xor(q4, mm);
        }
        if (lane == 0) {
            float Af = (float)A;
            float s1 = (Af - (float)(2.0 * d1)) + (float)q1;
            float s2 = (Af - (float)(2.0 * d2)) + (float)q2;
            float s3 = (Af - (float)(2.0 * d3)) + (float)q3;
            float s4 = (Af - (float)(2.0 * d4)) + (float)q4;
            float bv = s1; int bk = c1;
            if (lexlt(s2, c2, bv, bk)) { bv = s2; bk = c2; }
            if (lexlt(s3, c3, bv, bk)) { bv = s3; bk = c3; }
            if (lexlt(s4, c4, bv, bk)) { bv = s4; bk = c4; }
            out[IDX_OFF + gidx] = (float)bk;
        }
    }
}

// ---- K2b: full exact rescan, grid-stride blocks (R12-proven) ----
__global__ __launch_bounds__(256) void vq_resolve_full(const float* __restrict__ z,
                                                       const float* __restrict__ e,
                                                       float* __restrict__ out) {
    __shared__ float zs[DIM];
    __shared__ float rv[4];
    __shared__ int ri[4];
    const int tid = threadIdx.x;
    const int wave = tid >> 6, lane = tid & 63;
    const unsigned n = reinterpret_cast<const unsigned*>(out + CNT_OFF)[1];
    const unsigned* list = reinterpret_cast<const unsigned*>(out + FULL_OFF);
    for (unsigned ei = blockIdx.x; ei < n; ei += gridDim.x) {
        const int gidx = (int)list[ei];
        const int b = gidx >> 14, m = gidx & (MB - 1);
        const float* zr = z + (size_t)b * DIM * MB + m;
        if (tid < DIM) zs[tid] = zr[(size_t)tid * MB];
        __syncthreads();
        double av = 0.0;
        #pragma unroll
        for (int t2 = 0; t2 < 4; ++t2) {
            double zv = (double)zs[lane * 4 + t2];
            av = fma(zv, zv, av);
        }
        #pragma unroll
        for (int mm = 1; mm < 64; mm <<= 1) av += __shfl_xor(av, mm);
        const float Af = (float)av;

        float bsv = FLT_MAX; int bsk = 0;
        for (int kk = 0; kk < 16; ++kk) {
            const int k = kk * 256 + tid;          // ascending per thread
            const float4* er4 = reinterpret_cast<const float4*>(e + (size_t)k * DIM);
            const float4* zs4 = reinterpret_cast<const float4*>(zs);
            double dot0 = 0.0, dot1 = 0.0, q0 = 0.0, q1 = 0.0;
            #pragma unroll 8
            for (int d4 = 0; d4 < 64; ++d4) {
                float4 ev = er4[d4];
                float4 zv = zs4[d4];
                dot0 = fma((double)zv.x, (double)ev.x, dot0);
                dot1 = fma((double)zv.y, (double)ev.y, dot1);
                dot0 = fma((double)zv.z, (double)ev.z, dot0);
                dot1 = fma((double)zv.w, (double)ev.w, dot1);
                q0 = fma((double)ev.x, (double)ev.x, q0);
                q1 = fma((double)ev.y, (double)ev.y, q1);
                q0 = fma((double)ev.z, (double)ev.z, q0);
                q1 = fma((double)ev.w, (double)ev.w, q1);
            }
            float s = (Af - (float)(2.0 * (dot0 + dot1))) + (float)(q0 + q1);
            if (s < bsv) { bsv = s; bsk = k; }
        }
        #pragma unroll
        for (int mm = 1; mm < 64; mm <<= 1) {
            float ov = __shfl_xor(bsv, mm);
            int oi = __shfl_xor(bsk, mm);
            if (ov < bsv || (ov == bsv && oi < bsk)) { bsv = ov; bsk = oi; }
        }
        if (lane == 0) { rv[wave] = bsv; ri[wave] = bsk; }
        __syncthreads();
        if (tid == 0) {
            float bv = rv[0]; int bk = ri[0];
            #pragma unroll
            for (int wv = 1; wv < 4; ++wv) {
                if (rv[wv] < bv || (rv[wv] == bv && ri[wv] < bk)) { bv = rv[wv]; bk = ri[wv]; }
            }
            out[IDX_OFF + gidx] = (float)bk;
        }
        __syncthreads();
    }
}

// ---- K3: z_q scatter + fused loss; e-rows staged in LDS (R12-proven) ----
__global__ __launch_bounds__(256) void vq_apply(const float* __restrict__ z,
                                                const float* __restrict__ e,
                                                float* __restrict__ out) {
    __shared__ int lds_fi[64];
    __shared__ float lds_e[64][260];
    __shared__ double lds_ls[4];
    const int tid = threadIdx.x;
    const int wave = tid >> 6, lane = tid & 63;
    const int nbase = blockIdx.x * 64;
    const int b = nbase / MB;
    const int mbase = nbase % MB;
    if (tid < 64) lds_fi[tid] = (int)out[IDX_OFF + nbase + tid];
    __syncthreads();
    for (int r = wave; r < 64; r += 4) {
        int code = lds_fi[r];
        float4 v = reinterpret_cast<const float4*>(e + (size_t)code * DIM)[lane];
        *reinterpret_cast<float4*>(&lds_e[r][lane * 4]) = v;
    }
    __syncthreads();

    double lsum = 0.0;
    const int mloc = tid & 63;
    const int d0 = tid >> 6;
    #pragma unroll 4
    for (int d = d0; d < DIM; d += 4) {
        float ev = lds_e[mloc][d];
        size_t off = (size_t)b * (DIM * MB) + (size_t)d * MB + mbase + mloc;
        float zv = z[off];
        out[off] = ev;
        float diff = ev - zv;
        lsum += (double)diff * diff;
    }
    #pragma unroll
    for (int off = 32; off > 0; off >>= 1) lsum += __shfl_down(lsum, off);
    if (lane == 0) lds_ls[wave] = lsum;
    __syncthreads();
    if (tid == 0) {
        double t = lds_ls[0] + lds_ls[1] + lds_ls[2] + lds_ls[3];
        atomicAdd(out + LOSS_OFF, (float)(t * (1.25 / (double)ZELEMS)));
    }
}

extern "C" void kernel_launch(void* const* d_in, const int* in_sizes, int n_in,
                              void* d_out, int out_size, void* d_ws, size_t ws_size,
                              hipStream_t stream) {
    const float* z = (const float*)d_in[0];    // [4,256,16,32,32] fp32
    const float* e = (const float*)d_in[1];    // [4096,256] fp32
    float* out = (float*)d_out;

    hipMemsetAsync(out + LOSS_OFF, 0, sizeof(float), stream);
    hipMemsetAsync(out + CNT_OFF, 0, 2 * sizeof(unsigned), stream);
    vq_prep<<<1536, 256, 0, stream>>>(e, out);
    vq_fast<<<NTOT / 128, 256, 0, stream>>>(z, out);
    vq_resolve_cand<<<256, 256, 0, stream>>>(z, e, out);
    vq_resolve_full<<<512, 256, 0, stream>>>(z, e, out);
    vq_apply<<<NTOT / 64, 256, 0, stream>>>(z, e, out);
}

// Round 18
// 518.800 us; speedup vs baseline: 2.3002x; 2.3002x over previous
//
#include <hip/hip_runtime.h>
#include <float.h>

#define KC 4096
#define DIM 256
#define MB 16384            // m per batch element (16*32*32)
#define NTOT 65536          // rows
#define ZELEMS 16777216
#define LOSS_OFF 16777216
#define IDX_OFF  16777217
// TAU: 2*(grid ULP(256)=3.05e-5) + 2*fp16-chain score err (<=4.7e-5 worst) + slack.
// Validated empirically at 1.5e-4 in R11-R17 (0 misses across 65536 rows).
#define TAU 1.5e-4f

// scratch inside z_q output region (fully overwritten by vq_apply at the end):
// [0, 524288)       fp16 e' A-fragment table (2MB)
#define BT_OFF   524288     // f32 |e_k|^2 table, 4096 floats
#define CNT_OFF  528400     // 2 uints (cand count, full count)
#define CAND_OFF 532480     // uint4 entries (16B each), cap 65536
#define FULL_OFF 800000     // uint entries, cap 65536

typedef _Float16 h8 __attribute__((ext_vector_type(8)));
typedef float f4v __attribute__((ext_vector_type(4)));

__device__ __forceinline__ bool lexlt(float av, int ai, float bv, int bi) {
    return (av < bv) || (av == bv && ai < bi);
}

// ---- P: fused prep. Blocks 0-511: fp16 e'=e*4096 A-frag table (R10-R17
// verified geometry). Blocks 512-1535: |e|^2 (fp64->f32), one wave per code. ----
__global__ __launch_bounds__(256) void vq_prep(const float* __restrict__ e,
                                               float* __restrict__ out) {
    if (blockIdx.x < 512) {
        int t = blockIdx.x * 256 + threadIdx.x;        // 0..131071
        int code = t >> 5, s8 = t & 31;
        const float4* src = reinterpret_cast<const float4*>(e + (size_t)code * DIM + s8 * 8);
        float4 v0 = src[0], v1 = src[1];
        float f[8] = {v0.x, v0.y, v0.z, v0.w, v1.x, v1.y, v1.z, v1.w};
        union { uint4 q; _Float16 h[8]; } P;
        #pragma unroll
        for (int p = 0; p < 8; ++p) P.h[p] = (_Float16)(f[p] * 4096.0f);
        int kc = s8 >> 2, khi = s8 & 3;
        int lane = khi * 16 + (code & 15);
        int slot = ((code >> 4) * 8 + kc) * 64 + lane;
        reinterpret_cast<uint4*>(out)[slot] = P.q;
    } else {
        int k = (blockIdx.x - 512) * 4 + (threadIdx.x >> 6);   // 0..4095
        int lane = threadIdx.x & 63;
        float4 v = reinterpret_cast<const float4*>(e + (size_t)k * DIM)[lane];
        double s = (double)v.x * v.x + (double)v.y * v.y + (double)v.z * v.z + (double)v.w * v.w;
        #pragma unroll
        for (int off = 32; off > 0; off >>= 1) s += __shfl_down(s, off);
        if (lane == 0) out[BT_OFF + k] = (float)s;
    }
}

// sorted insert keeping the 4 SMALLEST pushed (v0<=v1<=v2<=v3); exact-loss
// guarantee: any evicted value >= v3, so a lost window member forces v3<=thr
// -> n=5 -> full. No overflow counter needed.
#define INS4(V0, V1, V2, V3, L0, L1, L2, L3, v, k)                              \
    if (v < V3) {                                                               \
        if (v < V2) {                                                           \
            V3 = V2; L3 = L2;                                                   \
            if (v < V1) {                                                       \
                V2 = V1; L2 = L1;                                               \
                if (v < V0) { V1 = V0; L1 = L0; V0 = v; L0 = k; }               \
                else        { V1 = v; L1 = k; }                                 \
            } else { V2 = v; L2 = k; }                                          \
        } else { V3 = v; L3 = k; }                                              \
    }

// ---- K1: fp16 MFMA, SINGLE-PASS exact-window. Block = 128 rows (4w x 32r).
// Per lane: (b1,bk) + 4 smallest (value,k) among pushes (scores within tau of
// running min + displaced records). End: filter vs FINAL gb1+TAU (exact). ----
__global__ __launch_bounds__(256) void vq_fast(const float* __restrict__ z,
                                               float* __restrict__ out) {
    __shared__ uint4 etile[2][512];                // 16KB double-buffered tile
    __shared__ unsigned long long lists[4][32][4]; // (wave,row,khi) packed lists
    const int tid = threadIdx.x;
    const int wave = tid >> 6, lane = tid & 63;
    const int khi = lane >> 4, l16 = lane & 15;
    const int nbase = blockIdx.x * 128;
    const int b = nbase / MB;
    const int mbase = nbase % MB;
    const float* zb = z + (size_t)b * DIM * MB + mbase + wave * 32 + l16;

    // z B-fragments (fp16), 2 row-sets x 8 kc
    h8 zf0[8], zf1[8];
    #pragma unroll
    for (int kc = 0; kc < 8; ++kc) {
        h8 va, vb;
        #pragma unroll
        for (int j = 0; j < 8; ++j) {
            size_t off = (size_t)(kc * 32 + khi * 8 + j) * MB;
            va[j] = (_Float16)zb[off];
            vb[j] = (_Float16)zb[off + 16];
        }
        zf0[kc] = va; zf1[kc] = vb;
    }

    const uint4* ET = reinterpret_cast<const uint4*>(out);
    const float* Btab = out + BT_OFF;

    float b10 = FLT_MAX, b11 = FLT_MAX;
    int bk0 = 0, bk1 = 0;
    float v00 = FLT_MAX, v01 = FLT_MAX, v02 = FLT_MAX, v03 = FLT_MAX;
    float v10 = FLT_MAX, v11 = FLT_MAX, v12 = FLT_MAX, v13 = FLT_MAX;
    int l00 = 0, l01 = 0, l02 = 0, l03 = 0;
    int l10 = 0, l11 = 0, l12 = 0, l13 = 0;

    uint4 r0 = ET[tid], r1 = ET[tid + 256];        // preload tile 0
    for (int tile = 0; tile < KC / 16; ++tile) {
        const int cur = tile & 1;
        etile[cur][tid] = r0; etile[cur][tid + 256] = r1;
        __syncthreads();                           // ONLY barrier per tile:
        // write(t+2) to this buffer is separated from read(t) by barrier(t+1)
        if (tile < KC / 16 - 1) {
            r0 = ET[(size_t)(tile + 1) * 512 + tid];
            r1 = ET[(size_t)(tile + 1) * 512 + tid + 256];
        }

        f4v a0 = {0.f, 0.f, 0.f, 0.f}, a1 = a0;
        #pragma unroll
        for (int kc = 0; kc < 8; ++kc) {
            union { uint4 q; h8 v; } af;
            af.q = etile[cur][kc * 64 + lane];
            a0 = __builtin_amdgcn_mfma_f32_16x16x32_f16(af.v, zf0[kc], a0, 0, 0, 0);
            a1 = __builtin_amdgcn_mfma_f32_16x16x32_f16(af.v, zf1[kc], a1, 0, 0, 0);
        }

        const f4v Bv = *reinterpret_cast<const f4v*>(Btab + tile * 16 + khi * 4);
        const int kb = tile * 16 + khi * 4;
        float sc0[4], sc1[4];
        #pragma unroll
        for (int i = 0; i < 4; ++i) {
            sc0[i] = fmaf(-4.8828125e-4f, a0[i], Bv[i]);   // -1/2048 exact
            sc1[i] = fmaf(-4.8828125e-4f, a1[i], Bv[i]);
        }
        float m0 = fminf(fminf(sc0[0], sc0[1]), fminf(sc0[2], sc0[3]));
        if (m0 <= b10 + TAU) {                     // rare: detail insert
            #pragma unroll
            for (int i = 0; i < 4; ++i) {
                float s = sc0[i]; int k = kb + i;  // ascending k per lane
                if (s < b10) {
                    if (b10 <= s + TAU) INS4(v00, v01, v02, v03, l00, l01, l02, l03, b10, bk0)
                    b10 = s; bk0 = k;
                } else if (s <= b10 + TAU) {
                    INS4(v00, v01, v02, v03, l00, l01, l02, l03, s, k)
                }
            }
        }
        float m1 = fminf(fminf(sc1[0], sc1[1]), fminf(sc1[2], sc1[3]));
        if (m1 <= b11 + TAU) {
            #pragma unroll
            for (int i = 0; i < 4; ++i) {
                float s = sc1[i]; int k = kb + i;
                if (s < b11) {
                    if (b11 <= s + TAU) INS4(v10, v11, v12, v13, l10, l11, l12, l13, b11, bk1)
                    b11 = s; bk1 = k;
                } else if (s <= b11 + TAU) {
                    INS4(v10, v11, v12, v13, l10, l11, l12, l13, s, k)
                }
            }
        }
    }

    // merge top-1 across the 4 khi groups (lex), keep own (b1,bk) intact
    float gb0 = b10, gb1 = b11;
    int gk0 = bk0, gk1 = bk1;
    #pragma unroll
    for (int off = 16; off < 64; off <<= 1) {
        float ov = __shfl_xor(gb0, off); int ok = __shfl_xor(gk0, off);
        if (lexlt(ov, ok, gb0, gk0)) { gb0 = ov; gk0 = ok; }
        ov = __shfl_xor(gb1, off); ok = __shfl_xor(gk1, off);
        if (lexlt(ov, ok, gb1, gk1)) { gb1 = ov; gk1 = ok; }
    }
    const float thr0 = gb0 + TAU, thr1 = gb1 + TAU;

    // exact-filter own entries vs FINAL threshold, pack (<=4 ks + count<=5)
    int n0 = 0, pa0 = 0, pb0 = 0, pc0 = 0, pd0 = 0;
    #define ADD0(kk) { if (n0 == 0) pa0 = kk; else if (n0 == 1) pb0 = kk; \
                       else if (n0 == 2) pc0 = kk; else if (n0 == 3) pd0 = kk; n0++; }
    if (b10 <= thr0) ADD0(bk0)
    if (v00 <= thr0) ADD0(l00)
    if (v01 <= thr0) ADD0(l01)
    if (v02 <= thr0) ADD0(l02)
    if (v03 <= thr0) ADD0(l03)
    int n1 = 0, pa1 = 0, pb1 = 0, pc1 = 0, pd1 = 0;
    #define ADD1(kk) { if (n1 == 0) pa1 = kk; else if (n1 == 1) pb1 = kk; \
                       else if (n1 == 2) pc1 = kk; else if (n1 == 3) pd1 = kk; n1++; }
    if (b11 <= thr1) ADD1(bk1)
    if (v10 <= thr1) ADD1(l10)
    if (v11 <= thr1) ADD1(l11)
    if (v12 <= thr1) ADD1(l12)
    if (v13 <= thr1) ADD1(l13)
    lists[wave][l16][khi] = ((unsigned long long)n0 << 48) |
        (unsigned long long)pa0 | ((unsigned long long)pb0 << 12) |
        ((unsigned long long)pc0 << 24) | ((unsigned long long)pd0 << 36);
    lists[wave][16 + l16][khi] = ((unsigned long long)n1 << 48) |
        (unsigned long long)pa1 | ((unsigned long long)pb1 << 12) |
        ((unsigned long long)pc1 << 24) | ((unsigned long long)pd1 << 36);
    __syncthreads();

    // gather + classify + emit (lanes<16 own one row per set)
    unsigned* cntg = (unsigned*)(out + CNT_OFF);
    #pragma unroll
    for (int set = 0; set < 2; ++set) {
        bool act = (lane < 16);
        int gidx = nbase + wave * 32 + set * 16 + l16;
        int I1 = set ? gk1 : gk0;
        int tot = 0, c[4];
        c[0] = c[1] = c[2] = c[3] = I1;            // pad with best (harmless dup)
        if (act) {
            #pragma unroll
            for (int q = 0; q < 4; ++q) {
                unsigned long long pl = lists[wave][set * 16 + l16][q];
                int pc = (int)(pl >> 48);
                #pragma unroll
                for (int j = 0; j < 4; ++j) {
                    int kv = (int)((pl >> (12 * j)) & 4095ull);
                    if (j < pc && tot + j < 4) c[tot + j] = kv;
                }
                tot += pc;
            }
            out[IDX_OFF + gidx] = (float)I1;       // final for clean; placeholder else
        }
        bool cand = act && (tot >= 2) && (tot <= 4);
        bool full = act && (tot > 4);
        unsigned long long mc = __ballot(cand);
        if (mc) {
            int leader = __ffsll((long long)mc) - 1;
            unsigned base = 0;
            if (lane == leader) base = atomicAdd(cntg, (unsigned)__popcll(mc));
            base = __shfl(base, leader);
            if (cand) {
                unsigned pos = base + (unsigned)__popcll(mc & ((1ull << lane) - 1ull));
                reinterpret_cast<uint4*>(out + CAND_OFF)[pos] =
                    make_uint4((unsigned)gidx,
                               (unsigned)c[0] | ((unsigned)c[1] << 16),
                               (unsigned)c[2] | ((unsigned)c[3] << 16), 0u);
            }
        }
        unsigned long long mf = __ballot(full);
        if (mf) {
            int leader = __ffsll((long long)mf) - 1;
            unsigned base = 0;
            if (lane == leader) base = atomicAdd(cntg + 1, (unsigned)__popcll(mf));
            base = __shfl(base, leader);
            if (full) {
                unsigned pos = base + (unsigned)__popcll(mf & ((1ull << lane) - 1ull));
                reinterpret_cast<unsigned*>(out + FULL_OFF)[pos] = (unsigned)gidx;
            }
        }
    }
}

// ---- K2a: candidate rescore (<=4 codes), B from Btab, grid-stride waves ----
__global__ __launch_bounds__(256) void vq_resolve_cand(const float* __restrict__ z,
                                                       const float* __restrict__ e,
                                                       float* __restrict__ out) {
    const int wave = threadIdx.x >> 6, lane = threadIdx.x & 63;
    const unsigned n = *reinterpret_cast<const unsigned*>(out + CNT_OFF);
    const uint4* list = reinterpret_cast<const uint4*>(out + CAND_OFF);
    const float* Btab = out + BT_OFF;
    for (unsigned ei = blockIdx.x * 4 + wave; ei < n; ei += gridDim.x * 4) {
        uint4 ent = list[ei];
        const int gidx = (int)ent.x;
        const int c1 = (int)(ent.y & 0xFFFFu), c2 = (int)(ent.y >> 16);
        const int c3 = (int)(ent.z & 0xFFFFu), c4 = (int)(ent.z >> 16);
        const int b = gidx >> 14, m = gidx & (MB - 1);
        const float* zr = z + (size_t)b * DIM * MB + m;
        const float* e1 = e + (size_t)c1 * DIM;
        const float* e2 = e + (size_t)c2 * DIM;
        const float* e3 = e + (size_t)c3 * DIM;
        const float* e4 = e + (size_t)c4 * DIM;
        double A = 0.0;
        double d1 = 0.0, d2 = 0.0, d3 = 0.0, d4 = 0.0;
        #pragma unroll
        for (int jj = 0; jj < 4; ++jj) {
            int d = lane * 4 + jj;
            double zv = (double)zr[(size_t)d * MB];
            A = fma(zv, zv, A);
            d1 = fma(zv, (double)e1[d], d1);
            d2 = fma(zv, (double)e2[d], d2);
            d3 = fma(zv, (double)e3[d], d3);
            d4 = fma(zv, (double)e4[d], d4);
        }
        #pragma unroll
        for (int mm = 1; mm < 64; mm <<= 1) {
            A += __shfl_xor(A, mm);
            d1 += __shfl_xor(d1, mm); d2 += __shfl_xor(d2, mm);
            d3 += __shfl_xor(d3, mm); d4 += __shfl_xor(d4, mm);
        }
        if (lane == 0) {
            float Af = (float)A;
            float s1 = (Af - (float)(2.0 * d1)) + Btab[c1];
            float s2 = (Af - (float)(2.0 * d2)) + Btab[c2];
            float s3 = (Af - (float)(2.0 * d3)) + Btab[c3];
            float s4 = (Af - (float)(2.0 * d4)) + Btab[c4];
            float bv = s1; int bk = c1;
            if (lexlt(s2, c2, bv, bk)) { bv = s2; bk = c2; }
            if (lexlt(s3, c3, bv, bk)) { bv = s3; bk = c3; }
            if (lexlt(s4, c4, bv, bk)) { bv = s4; bk = c4; }
            out[IDX_OFF + gidx] = (float)bk;
        }
    }
}

// ---- K2b: full exact rescan, B from Btab, grid-stride blocks ----
__global__ __launch_bounds__(256) void vq_resolve_full(const float* __restrict__ z,
                                                       const float* __restrict__ e,
                                                       float* __restrict__ out) {
    __shared__ float zs[DIM];
    __shared__ float rv[4];
    __shared__ int ri[4];
    const int tid = threadIdx.x;
    const int wave = tid >> 6, lane = tid & 63;
    const unsigned n = reinterpret_cast<const unsigned*>(out + CNT_OFF)[1];
    const unsigned* list = reinterpret_cast<const unsigned*>(out + FULL_OFF);
    const float* Btab = out + BT_OFF;
    for (unsigned ei = blockIdx.x; ei < n; ei += gridDim.x) {
        const int gidx = (int)list[ei];
        const int b = gidx >> 14, m = gidx & (MB - 1);
        const float* zr = z + (size_t)b * DIM * MB + m;
        if (tid < DIM) zs[tid] = zr[(size_t)tid * MB];
        __syncthreads();
        double av = 0.0;
        #pragma unroll
        for (int t2 = 0; t2 < 4; ++t2) {
            double zv = (double)zs[lane * 4 + t2];
            av = fma(zv, zv, av);
        }
        #pragma unroll
        for (int mm = 1; mm < 64; mm <<= 1) av += __shfl_xor(av, mm);
        const float Af = (float)av;

        float bsv = FLT_MAX; int bsk = 0;
        for (int kk = 0; kk < 16; ++kk) {
            const int k = kk * 256 + tid;          // ascending per thread
            const float4* er4 = reinterpret_cast<const float4*>(e + (size_t)k * DIM);
            const float4* zs4 = reinterpret_cast<const float4*>(zs);
            double dot0 = 0.0, dot1 = 0.0;
            #pragma unroll 8
            for (int d4 = 0; d4 < 64; ++d4) {
                float4 ev = er4[d4];
                float4 zv = zs4[d4];
                dot0 = fma((double)zv.x, (double)ev.x, dot0);
                dot1 = fma((double)zv.y, (double)ev.y, dot1);
                dot0 = fma((double)zv.z, (double)ev.z, dot0);
                dot1 = fma((double)zv.w, (double)ev.w, dot1);
            }
            float s = (Af - (float)(2.0 * (dot0 + dot1))) + Btab[k];
            if (s < bsv) { bsv = s; bsk = k; }
        }
        #pragma unroll
        for (int mm = 1; mm < 64; mm <<= 1) {
            float ov = __shfl_xor(bsv, mm);
            int oi = __shfl_xor(bsk, mm);
            if (ov < bsv || (ov == bsv && oi < bsk)) { bsv = ov; bsk = oi; }
        }
        if (lane == 0) { rv[wave] = bsv; ri[wave] = bsk; }
        __syncthreads();
        if (tid == 0) {
            float bv = rv[0]; int bk = ri[0];
            #pragma unroll
            for (int wv = 1; wv < 4; ++wv) {
                if (rv[wv] < bv || (rv[wv] == bv && ri[wv] < bk)) { bv = rv[wv]; bk = ri[wv]; }
            }
            out[IDX_OFF + gidx] = (float)bk;
        }
        __syncthreads();
    }
}

// ---- K3: z_q scatter + fused loss; e-rows staged in LDS (R12-proven) ----
__global__ __launch_bounds__(256) void vq_apply(const float* __restrict__ z,
                                                const float* __restrict__ e,
                                                float* __restrict__ out) {
    __shared__ int lds_fi[64];
    __shared__ float lds_e[64][260];
    __shared__ double lds_ls[4];
    const int tid = threadIdx.x;
    const int wave = tid >> 6, lane = tid & 63;
    const int nbase = blockIdx.x * 64;
    const int b = nbase / MB;
    const int mbase = nbase % MB;
    if (tid < 64) lds_fi[tid] = (int)out[IDX_OFF + nbase + tid];
    __syncthreads();
    for (int r = wave; r < 64; r += 4) {
        int code = lds_fi[r];
        float4 v = reinterpret_cast<const float4*>(e + (size_t)code * DIM)[lane];
        *reinterpret_cast<float4*>(&lds_e[r][lane * 4]) = v;
    }
    __syncthreads();

    double lsum = 0.0;
    const int mloc = tid & 63;
    const int d0 = tid >> 6;
    #pragma unroll 4
    for (int d = d0; d < DIM; d += 4) {
        float ev = lds_e[mloc][d];
        size_t off = (size_t)b * (DIM * MB) + (size_t)d * MB + mbase + mloc;
        float zv = z[off];
        out[off] = ev;
        float diff = ev - zv;
        lsum += (double)diff * diff;
    }
    #pragma unroll
    for (int off = 32; off > 0; off >>= 1) lsum += __shfl_down(lsum, off);
    if (lane == 0) lds_ls[wave] = lsum;
    __syncthreads();
    if (tid == 0) {
        double t = lds_ls[0] + lds_ls[1] + lds_ls[2] + lds_ls[3];
        atomicAdd(out + LOSS_OFF, (float)(t * (1.25 / (double)ZELEMS)));
    }
}

extern "C" void kernel_launch(void* const* d_in, const int* in_sizes, int n_in,
                              void* d_out, int out_size, void* d_ws, size_t ws_size,
                              hipStream_t stream) {
    const float* z = (const float*)d_in[0];    // [4,256,16,32,32] fp32
    const float* e = (const float*)d_in[1];    // [4096,256] fp32
    float* out = (float*)d_out;

    hipMemsetAsync(out + LOSS_OFF, 0, sizeof(float), stream);
    hipMemsetAsync(out + CNT_OFF, 0, 2 * sizeof(unsigned), stream);
    vq_prep<<<1536, 256, 0, stream>>>(e, out);
    vq_fast<<<NTOT / 128, 256, 0, stream>>>(z, out);
    vq_resolve_cand<<<1024, 256, 0, stream>>>(z, e, out);
    vq_resolve_full<<<512, 256, 0, stream>>>(z, e, out);
    vq_apply<<<NTOT / 64, 256, 0, stream>>>(z, e, out);
}